// Round 19
// baseline (1838.070 us; speedup 1.0000x reference)
//
#include <hip/hip_runtime.h>
#include <math.h>

// ---------------------------------------------------------------------------
// Heterogeneous GraphSAGE (3 types, 6 relations, D=128, L=3) + MLP head.
// Round 19: dual-relation fused sage (one dispatch/layer): per wave,
// {gather->Ms, 3-term MFMA, l2norm, o+=} for relation A then B, single
// relu+store. Bit-identical to R18's slot pair (saves xdst re-read + output
// RMW, ~420MB/layer). Head GEMMs also drop to 3-term (split residual proven
// sub-floor in R18). Slot-major phase A, col prefetch, 32KB swizzled Ms,
// no barriers (wave-private stripes; same-wave LDS ops are in-order).
//
// Node row layout: [performance 0..200000) [artist ..230000) [song ..280000)
// ---------------------------------------------------------------------------

#define NPF 200000
#define NAR 30000
#define NSO 50000
#define NDTOT 560000     // sum of per-relation dst-node counts
#define ETOT  1900000    // total edges
#define VPT 12
#define SCAN_CHUNK (256 * VPT)   // 3072
#define SCAN_NB 183              // ceil(560000/3072)

// per-type 64-row block counts and the merged grid
#define BLKP 3125                // 200000/64
#define BLKA 469                 // ceil(30000/64)
#define BLKS 782                 // ceil(50000/64)
#define BLKTOT (BLKP + BLKA + BLKS)   // 4376

typedef __attribute__((ext_vector_type(8))) short bf16x8;
typedef __attribute__((ext_vector_type(4))) float f32x4;

__device__ __forceinline__ unsigned short f2bf(float f) {
  union { float f; unsigned u; } v; v.f = f;
  unsigned u = v.u;
  u += 0x7FFFu + ((u >> 16) & 1u);
  return (unsigned short)(u >> 16);
}
__device__ __forceinline__ float bf2f(unsigned short h) {
  union { unsigned u; float f; } v; v.u = ((unsigned)h) << 16;
  return v.f;
}

struct BF3 { short h, m, l; };
__device__ __forceinline__ BF3 split3(float f) {
  BF3 r;
  unsigned short hh = f2bf(f);
  float r1 = f - bf2f(hh);
  unsigned short mm = f2bf(r1);
  float r2 = r1 - bf2f(mm);
  r.h = (short)hh; r.m = (short)mm; r.l = (short)f2bf(r2);
  return r;
}
struct BF2 { short h, m; };
__device__ __forceinline__ BF2 split2(float f) {
  BF2 r;
  unsigned short hh = f2bf(f);
  r.h = (short)hh;
  r.m = (short)f2bf(f - bf2f(hh));
  return r;
}

#define MFMA3(ah, am, bh, bm, acc)                                              \
  acc = __builtin_amdgcn_mfma_f32_16x16x32_bf16(ah, bh, acc, 0, 0, 0);          \
  acc = __builtin_amdgcn_mfma_f32_16x16x32_bf16(am, bh, acc, 0, 0, 0);          \
  acc = __builtin_amdgcn_mfma_f32_16x16x32_bf16(ah, bm, acc, 0, 0, 0);

// block -> (type, local block) decode for the merged 4376-block grids
__device__ __forceinline__ void blk_decode(int b, int* t, int* lb) {
  if (b < BLKP)             { *t = 0; *lb = b; }
  else if (b < BLKP + BLKA) { *t = 1; *lb = b - BLKP; }
  else                      { *t = 2; *lb = b - BLKP - BLKA; }
}

// ---------- fused gather x0 = emb[nid] over all 3 types ----------
__global__ void k_gather_all(const int* __restrict__ nidP, const int* __restrict__ nidA,
                             const int* __restrict__ nidS,
                             const float4* __restrict__ embP, const float4* __restrict__ embA,
                             const float4* __restrict__ embS, float4* __restrict__ dst) {
  int i = blockIdx.x * blockDim.x + threadIdx.x;
  if (i >= 280000 * 32) return;
  int r = i >> 5, c = i & 31;
  const int* nid; const float4* emb; int lr;
  if (r < NPF)            { nid = nidP; emb = embP; lr = r; }
  else if (r < NPF + NAR) { nid = nidA; emb = embA; lr = r - NPF; }
  else                    { nid = nidS; emb = embS; lr = r - NPF - NAR; }
  dst[(size_t)r * 32 + c] = emb[(size_t)nid[lr] * 32 + c];
}

// ---------- concatenated CSR build over all 6 relations ----------
__device__ __forceinline__ void edge_decode(int i,
    const int* e0, const int* e1, const int* e2, const int* e3, const int* e4, const int* e5,
    const int** eg, int* lo, int* E, int* co) {
  if (i < 400000)       { *eg = e0; *lo = i;           *E = 400000; *co = 0; }
  else if (i < 800000)  { *eg = e1; *lo = i - 400000;  *E = 400000; *co = 200000; }
  else if (i < 950000)  { *eg = e2; *lo = i - 800000;  *E = 150000; *co = 250000; }
  else if (i < 1350000) { *eg = e3; *lo = i - 950000;  *E = 400000; *co = 300000; }
  else if (i < 1750000) { *eg = e4; *lo = i - 1350000; *E = 400000; *co = 330000; }
  else                  { *eg = e5; *lo = i - 1750000; *E = 150000; *co = 530000; }
}

__global__ void k_count_all(const int* e0, const int* e1, const int* e2,
                            const int* e3, const int* e4, const int* e5,
                            int* __restrict__ cnt) {
  int i = blockIdx.x * blockDim.x + threadIdx.x;
  if (i >= ETOT) return;
  const int* eg; int lo, E, co;
  edge_decode(i, e0, e1, e2, e3, e4, e5, &eg, &lo, &E, &co);
  atomicAdd(&cnt[co + eg[E + lo]], 1);
}

__global__ void k_scan_block(const int* __restrict__ cnt, int n, int* __restrict__ part) {
  __shared__ int sd[256];
  int t = threadIdx.x;
  int base = blockIdx.x * SCAN_CHUNK + t * VPT;
  int s = 0;
#pragma unroll
  for (int i = 0; i < VPT; ++i) { int idx = base + i; if (idx < n) s += cnt[idx]; }
  sd[t] = s; __syncthreads();
  for (int off = 128; off > 0; off >>= 1) { if (t < off) sd[t] += sd[t + off]; __syncthreads(); }
  if (t == 0) part[blockIdx.x] = sd[0];
}

__global__ void k_scan_top(int* part, int nb) {
  __shared__ int sd[256];
  int t = threadIdx.x;
  int v = (t < nb) ? part[t] : 0;
  sd[t] = v; __syncthreads();
  for (int off = 1; off < 256; off <<= 1) {
    int add = (t >= off) ? sd[t - off] : 0;
    __syncthreads();
    sd[t] += add;
    __syncthreads();
  }
  if (t < nb) part[t] = sd[t] - v;  // exclusive
}

// also zeroes cnt so it can be reused as the fill cursor array
__global__ void k_scan_final(int* __restrict__ cnt, int n, const int* __restrict__ part,
                             int* __restrict__ rp, int E) {
  __shared__ int sd[256];
  int t = threadIdx.x;
  int base = blockIdx.x * SCAN_CHUNK + t * VPT;
  int v[VPT]; int s = 0;
#pragma unroll
  for (int i = 0; i < VPT; ++i) { int idx = base + i; v[i] = (idx < n) ? cnt[idx] : 0; s += v[i]; }
  sd[t] = s; __syncthreads();
  for (int off = 1; off < 256; off <<= 1) {
    int add = (t >= off) ? sd[t - off] : 0;
    __syncthreads();
    sd[t] += add;
    __syncthreads();
  }
  int run = part[blockIdx.x] + sd[t] - s;
#pragma unroll
  for (int i = 0; i < VPT; ++i) {
    int idx = base + i;
    if (idx < n) { rp[idx] = run; cnt[idx] = 0; }
    run += v[i];
  }
  if (blockIdx.x == 0 && t == 0) rp[n] = E;
}

__global__ void k_fill_all(const int* e0, const int* e1, const int* e2,
                           const int* e3, const int* e4, const int* e5,
                           const int* __restrict__ rp, int* __restrict__ cur,
                           int* __restrict__ col) {
  int i = blockIdx.x * blockDim.x + threadIdx.x;
  if (i >= ETOT) return;
  const int* eg; int lo, E, co;
  edge_decode(i, e0, e1, e2, e3, e4, e5, &eg, &lo, &E, &co);
  int d = co + eg[E + lo];
  int p = atomicAdd(&cur[d], 1);
  col[rp[d] + p] = eg[lo];
}

// ---------- pack weights into MFMA B-fragment order, bf16 hi/mid/lo ----------
// matrix m: [0,18)=Wl[layer*6+r], [18,36)=Wr, [36,39)=pw1[type], [39,42)=pw2[type]
#define PKSTRIDE 49152
__global__ void k_packW(const float* __restrict__ Wl, const float* __restrict__ Wr,
                        const float* __restrict__ pw1, const float* __restrict__ pw2,
                        unsigned short* __restrict__ pk) {
  int gid = blockIdx.x * blockDim.x + threadIdx.x;
  if (gid >= 42 * 4 * 8 * 64) return;
  int lane = gid & 63;
  int t = (gid >> 6) & 7;
  int s = (gid >> 9) & 3;
  int m = gid >> 11;
  const float* src;
  if (m < 18) src = Wl + (size_t)m * 16384;
  else if (m < 36) src = Wr + (size_t)(m - 18) * 16384;
  else if (m < 39) src = pw1 + (size_t)(m - 36) * 16384;
  else src = pw2 + (size_t)(m - 39) * 16384;
  int n = t * 16 + (lane & 15);
  int k0 = s * 32 + (lane >> 4) * 8;
  unsigned short* hi = pk + (size_t)m * PKSTRIDE + ((size_t)(s * 8 + t) * 64 + lane) * 8;
  unsigned short* mid = hi + 16384;
  unsigned short* lo = hi + 32768;
#pragma unroll
  for (int j = 0; j < 8; ++j) {
    float f = src[(size_t)(k0 + j) * 128 + n];
    BF3 w = split3(f);
    hi[j] = (unsigned short)w.h;
    mid[j] = (unsigned short)w.m;
    lo[j] = (unsigned short)w.l;
  }
}

// ---------- dual-relation merged agg+SAGE, one dispatch per layer ----------
// Per wave (16 dst rows): for rel A then rel B:
//   phase A: segment mean -> swizzled Ms stripe (wave-private, no barrier)
//   phase B: acc = Ms@Wl + x@Wr (3-term split-bf16), +bias, l2norm -> o +=
// then relu? + single store. Relation order matches the reference sum order.
__global__ __launch_bounds__(256) void k_sage_merged2(
    const int* __restrict__ rp, const int* __restrict__ col,
    const float* __restrict__ xin, float* __restrict__ xout,
    const unsigned short* __restrict__ pkw, const float* __restrict__ bl,
    int layer, int relu_out) {
  __shared__ float Ms[64 * 128];   // 32768 B exactly
  static const int RELSLOT[2][3] = {{0, 3, 1}, {4, 5, 2}};
  static const int SRCT[2][3]    = {{1, 0, 0}, {2, 2, 1}};
  static const int CNT_OFF[6] = {0, 200000, 250000, 300000, 330000, 530000};
  static const int TOFFc[3] = {0, NPF, NPF + NAR};
  static const int TNc[3]   = {NPF, NAR, NSO};
  int ty, lb;
  blk_decode(blockIdx.x, &ty, &lb);
  const float* xdst = xin + (size_t)TOFFc[ty] * 128;
  float* outp = xout + (size_t)TOFFc[ty] * 128;
  int n_dst = TNc[ty];

  int lane = threadIdx.x & 63;
  int wave = threadIdx.x >> 6;
  int row0b = lb * 64;
  int row0 = row0b + wave * 16;
  int cg = lane & 15, qg = lane >> 4;
  int ar = min(row0 + cg, n_dst - 1);
  int lar = wave * 16 + cg;
  int kb = qg * 8;
  const float4* Mlar = (const float4*)&Ms[lar * 128];
  int swl = lar & 7;

  f32x4 o[8];
#pragma unroll
  for (int t = 0; t < 8; ++t) o[t] = (f32x4){0.f, 0.f, 0.f, 0.f};

#pragma unroll 1
  for (int r2 = 0; r2 < 2; ++r2) {
    int rel = RELSLOT[r2][ty];
    int m = layer * 6 + rel;
    const int* rpt = rp + CNT_OFF[rel];
    const float* xsrc = xin + (size_t)TOFFc[SRCT[r2][ty]] * 128;
    const unsigned short* pkl = pkw + (size_t)m * PKSTRIDE;
    const unsigned short* pkr = pkw + (size_t)(18 + m) * PKSTRIDE;
    const float* blv = bl + (size_t)m * 128;

    // ---- phase A: segment mean into this wave's Ms stripe (swizzled) ----
    {
      int g = lane >> 4, li = lane & 15;
      int c0 = li * 8;
      int bb[4], ne[4];
      int maxd = 0;
#pragma unroll
      for (int i = 0; i < 4; ++i) {
        int d = row0b + wave * 16 + g * 4 + i;
        int b = 0, e = 0;
        if (d < n_dst) { b = rpt[d]; e = rpt[d + 1]; }
        bb[i] = b; ne[i] = e - b;
        maxd = max(maxd, e - b);
      }
      f32x4 a0[4], a1[4];
#pragma unroll
      for (int i = 0; i < 4; ++i) { a0[i] = (f32x4){0.f,0.f,0.f,0.f}; a1[i] = (f32x4){0.f,0.f,0.f,0.f}; }
      int nc[4];
#pragma unroll
      for (int i = 0; i < 4; ++i) nc[i] = (0 < ne[i]) ? col[bb[i]] : 0;
      for (int k = 0; k < maxd; ++k) {
        int cc[4];
#pragma unroll
        for (int i = 0; i < 4; ++i) cc[i] = nc[i];
#pragma unroll
        for (int i = 0; i < 4; ++i) nc[i] = (k + 1 < ne[i]) ? col[bb[i] + k + 1] : 0;
#pragma unroll
        for (int i = 0; i < 4; ++i) {
          if (k < ne[i]) {
            const float* sp = xsrc + (size_t)cc[i] * 128 + c0;
            float4 v0 = *(const float4*)sp;
            float4 v1 = *(const float4*)(sp + 4);
            a0[i][0] += v0.x; a0[i][1] += v0.y; a0[i][2] += v0.z; a0[i][3] += v0.w;
            a1[i][0] += v1.x; a1[i][1] += v1.y; a1[i][2] += v1.z; a1[i][3] += v1.w;
          }
        }
      }
#pragma unroll
      for (int i = 0; i < 4; ++i) {
        float inv = (ne[i] > 0) ? 1.0f / (float)ne[i] : 0.0f;
        int lr = wave * 16 + g * 4 + i;
        float4* Mrow = (float4*)&Ms[lr * 128];
        int sw = lr & 7;
        Mrow[(li * 2) ^ sw]     = make_float4(a0[i][0]*inv, a0[i][1]*inv, a0[i][2]*inv, a0[i][3]*inv);
        Mrow[(li * 2 + 1) ^ sw] = make_float4(a1[i][0]*inv, a1[i][1]*inv, a1[i][2]*inv, a1[i][3]*inv);
      }
    }
    // no barrier: same-wave LDS ops execute in order (write->read, read->overwrite)

    // ---- phase B: 3-term split-bf16 MFMA ----
    f32x4 acc[8];
#pragma unroll
    for (int t = 0; t < 8; ++t) acc[t] = (f32x4){0.f, 0.f, 0.f, 0.f};

#pragma unroll
    for (int sm = 0; sm < 2; ++sm) {
      const unsigned short* pk = sm ? pkr : pkl;
#pragma unroll
      for (int s = 0; s < 4; ++s) {
        float4 f0, f1;
        if (sm) {
          const float* ap = xdst + (size_t)ar * 128 + s * 32 + kb;
          f0 = *(const float4*)ap;
          f1 = *(const float4*)(ap + 4);
        } else {
          int ch = s * 8 + qg * 2;
          f0 = Mlar[ch ^ swl];
          f1 = Mlar[(ch + 1) ^ swl];
        }
        float fa[8] = {f0.x, f0.y, f0.z, f0.w, f1.x, f1.y, f1.z, f1.w};
        bf16x8 ah, am;
#pragma unroll
        for (int j = 0; j < 8; ++j) {
          BF2 w = split2(fa[j]);
          ah[j] = w.h; am[j] = w.m;
        }
        const unsigned short* pb = pk + (size_t)s * 4096 + (size_t)lane * 8;
#pragma unroll
        for (int t = 0; t < 8; ++t) {
          bf16x8 bh = *(const bf16x8*)(pb + (size_t)t * 512);
          bf16x8 bm = *(const bf16x8*)(pb + (size_t)t * 512 + 16384);
          MFMA3(ah, am, bh, bm, acc[t]);
        }
      }
    }

    // bias + l2norm, accumulate into o
#pragma unroll
    for (int t = 0; t < 8; ++t) {
      float bv = blv[t * 16 + cg];
#pragma unroll
      for (int j = 0; j < 4; ++j) acc[t][j] += bv;
    }
#pragma unroll
    for (int j = 0; j < 4; ++j) {
      float s = 0.f;
#pragma unroll
      for (int t = 0; t < 8; ++t) s += acc[t][j] * acc[t][j];
      s += __shfl_xor(s, 1); s += __shfl_xor(s, 2);
      s += __shfl_xor(s, 4); s += __shfl_xor(s, 8);
      float sc = 1.0f / fmaxf(sqrtf(s), 1e-12f);
#pragma unroll
      for (int t = 0; t < 8; ++t) o[t][j] += acc[t][j] * sc;
    }
  }

  // relu + single store
#pragma unroll
  for (int j = 0; j < 4; ++j) {
    int r = row0 + qg * 4 + j;
    if (r < n_dst) {
      float* p = outp + (size_t)r * 128 + cg;
#pragma unroll
      for (int t = 0; t < 8; ++t) {
        float v = o[t][j];
        if (relu_out) v = fmaxf(v, 0.f);
        p[t * 16] = v;
      }
    }
  }
}

// ---------- merged LayerNorm over all 280000 rows ----------
__global__ __launch_bounds__(256) void k_ln_all(const float* __restrict__ in,
                                                float* __restrict__ out,
                                                const float* __restrict__ lng,
                                                const float* __restrict__ lnb) {
  int gid = blockIdx.x * blockDim.x + threadIdx.x;
  int r = gid >> 2, q = gid & 3;
  if (r >= NPF + NAR + NSO) return;
  int ty = (r < NPF) ? 0 : ((r < NPF + NAR) ? 1 : 2);
  const float* g = lng + ty * 128;
  const float* bvec = lnb + ty * 128;
  float v[32];
#pragma unroll
  for (int j = 0; j < 8; ++j) {
    float4 t4 = *(const float4*)(in + (size_t)r * 128 + q * 32 + j * 4);
    v[4 * j] = t4.x; v[4 * j + 1] = t4.y; v[4 * j + 2] = t4.z; v[4 * j + 3] = t4.w;
  }
  float s = 0.f, sq = 0.f;
#pragma unroll
  for (int j = 0; j < 32; ++j) { s += v[j]; sq += v[j] * v[j]; }
  s  += __shfl_xor(s, 1);  s  += __shfl_xor(s, 2);
  sq += __shfl_xor(sq, 1); sq += __shfl_xor(sq, 2);
  float mu = s * 0.0078125f;
  float var = sq * 0.0078125f - mu * mu;
  float rs = rsqrtf(var + 1e-5f);
#pragma unroll
  for (int j = 0; j < 8; ++j) {
    float o[4];
#pragma unroll
    for (int k = 0; k < 4; ++k) {
      int c = q * 32 + j * 4 + k;
      o[k] = (v[j * 4 + k] - mu) * rs * g[c] + bvec[c];
    }
    *(float4*)(out + (size_t)r * 128 + q * 32 + j * 4) = make_float4(o[0], o[1], o[2], o[3]);
  }
}

// ---------- merged head GEMM over all 3 types (3-term split) ----------
// stage 0: relu(LN@pw1+pb1)  (pk base 36);  stage 1: l2norm(h1@pw2+pb2) (pk base 39).
// In-place safe when outp==A.
__global__ __launch_bounds__(256) void k_gemm_all(
    const float* __restrict__ A, const unsigned short* __restrict__ pkw,
    const float* __restrict__ biasb, float* __restrict__ outp,
    int pkbase, int relu, int l2n) {
  static const int TOFFc[3] = {0, NPF, NPF + NAR};
  static const int TNc[3]   = {NPF, NAR, NSO};
  int ty, lb;
  blk_decode(blockIdx.x, &ty, &lb);
  const unsigned short* pk = pkw + (size_t)(pkbase + ty) * PKSTRIDE;
  const float* bias = biasb + ty * 128;
  const float* At = A + (size_t)TOFFc[ty] * 128;
  float* outt = outp + (size_t)TOFFc[ty] * 128;
  int n = TNc[ty];

  int lane = threadIdx.x & 63;
  int wave = threadIdx.x >> 6;
  int row0 = lb * 64 + wave * 16;
  int cg = lane & 15, qg = lane >> 4;
  int ar = min(row0 + cg, n - 1);
  int kb = qg * 8;

  f32x4 acc[8];
#pragma unroll
  for (int t = 0; t < 8; ++t) acc[t] = (f32x4){0.f, 0.f, 0.f, 0.f};

#pragma unroll
  for (int s = 0; s < 4; ++s) {
    const float* ap = At + (size_t)ar * 128 + s * 32 + kb;
    float4 f0 = *(const float4*)ap;
    float4 f1 = *(const float4*)(ap + 4);
    float fa[8] = {f0.x, f0.y, f0.z, f0.w, f1.x, f1.y, f1.z, f1.w};
    bf16x8 ah, am;
#pragma unroll
    for (int j = 0; j < 8; ++j) {
      BF2 w = split2(fa[j]);
      ah[j] = w.h; am[j] = w.m;
    }
    const unsigned short* pb = pk + (size_t)s * 4096 + (size_t)lane * 8;
#pragma unroll
    for (int t = 0; t < 8; ++t) {
      bf16x8 bh = *(const bf16x8*)(pb + (size_t)t * 512);
      bf16x8 bm = *(const bf16x8*)(pb + (size_t)t * 512 + 16384);
      MFMA3(ah, am, bh, bm, acc[t]);
    }
  }

#pragma unroll
  for (int t = 0; t < 8; ++t) {
    float bv = bias[t * 16 + cg];
#pragma unroll
    for (int j = 0; j < 4; ++j) acc[t][j] += bv;
  }

  float ss[4];
  if (l2n) {
#pragma unroll
    for (int j = 0; j < 4; ++j) {
      float s = 0.f;
#pragma unroll
      for (int t = 0; t < 8; ++t) s += acc[t][j] * acc[t][j];
      s += __shfl_xor(s, 1); s += __shfl_xor(s, 2);
      s += __shfl_xor(s, 4); s += __shfl_xor(s, 8);
      ss[j] = 1.0f / fmaxf(sqrtf(s), 1e-12f);
    }
  } else {
#pragma unroll
    for (int j = 0; j < 4; ++j) ss[j] = 1.0f;
  }

#pragma unroll
  for (int j = 0; j < 4; ++j) {
    int r = row0 + qg * 4 + j;
    if (r < n) {
      float* p = outt + (size_t)r * 128 + cg;
#pragma unroll
      for (int t = 0; t < 8; ++t) {
        float v = acc[t][j] * ss[j];
        if (relu) v = fmaxf(v, 0.f);
        p[t * 16] = v;
      }
    }
  }
}

// ---------------------------------------------------------------------------
extern "C" void kernel_launch(void* const* d_in, const int* in_sizes, int n_in,
                              void* d_out, int out_size, void* d_ws, size_t ws_size,
                              hipStream_t stream) {
  const int* nid[3] = {(const int*)d_in[0], (const int*)d_in[1], (const int*)d_in[2]};
  const int* eg[6];
  for (int r = 0; r < 6; ++r) eg[r] = (const int*)d_in[3 + r];
  const float* emb[3] = {(const float*)d_in[9], (const float*)d_in[10], (const float*)d_in[11]};
  const float* Wl  = (const float*)d_in[12];
  const float* bl  = (const float*)d_in[13];
  const float* Wr  = (const float*)d_in[14];
  const float* lng = (const float*)d_in[15];
  const float* lnb = (const float*)d_in[16];
  const float* pw1 = (const float*)d_in[17];
  const float* pb1 = (const float*)d_in[18];
  const float* pw2 = (const float*)d_in[19];
  const float* pb2 = (const float*)d_in[20];

  // workspace layout (~160 MB)
  float* cur = (float*)d_ws;                          // 280000*128 f32 (features + head scratch)
  int* col   = (int*)(cur + (size_t)280000 * 128);    // ETOT
  int* rp    = col + ETOT;                            // NDTOT+1
  int* cnt   = rp + NDTOT + 1;                        // NDTOT (counts, then fill cursors)
  int* part  = cnt + NDTOT;                           // 256
  size_t pk_off = ((size_t)((char*)(part + 256) - (char*)d_ws) + 255) & ~(size_t)255;
  unsigned short* pkw = (unsigned short*)((char*)d_ws + pk_off);  // 42*49152 ushorts = 4.03 MB
  float* dout = (float*)d_out;

  // pack all weights (42 matrices) into MFMA fragment order, bf16 hi/mid/lo
  k_packW<<<dim3(336), dim3(256), 0, stream>>>(Wl, Wr, pw1, pw2, pkw);

  // x0 = emb[nid] (all types, one kernel)
  k_gather_all<<<dim3((280000 * 32 + 255) / 256), dim3(256), 0, stream>>>(
      nid[0], nid[1], nid[2],
      (const float4*)emb[0], (const float4*)emb[1], (const float4*)emb[2],
      (float4*)cur);

  // concatenated CSR build (count -> scan (zeroes cnt) -> fill)
  hipMemsetAsync(cnt, 0, (size_t)NDTOT * 4, stream);
  k_count_all<<<dim3((ETOT + 255) / 256), dim3(256), 0, stream>>>(
      eg[0], eg[1], eg[2], eg[3], eg[4], eg[5], cnt);
  k_scan_block<<<dim3(SCAN_NB), dim3(256), 0, stream>>>(cnt, NDTOT, part);
  k_scan_top<<<dim3(1), dim3(256), 0, stream>>>(part, SCAN_NB);
  k_scan_final<<<dim3(SCAN_NB), dim3(256), 0, stream>>>(cnt, NDTOT, part, rp, ETOT);
  k_fill_all<<<dim3((ETOT + 255) / 256), dim3(256), 0, stream>>>(
      eg[0], eg[1], eg[2], eg[3], eg[4], eg[5], rp, cnt, col);

  // GNN layers; ping-pong cur <-> d_out (layer0: cur->dout, 1: dout->cur, 2: cur->dout)
  // ONE dual-relation dispatch per layer
  for (int layer = 0; layer < 3; ++layer) {
    float* xin  = (layer == 1) ? dout : cur;
    float* xout = (layer == 1) ? cur  : dout;
    int relu_o = (layer < 2) ? 1 : 0;
    k_sage_merged2<<<dim3(BLKTOT), dim3(256), 0, stream>>>(
        rp, col, xin, xout, pkw, bl, layer, relu_o);
  }

  // head (merged over types): LN dout->cur, GEMM1 relu cur->cur (in-place),
  // GEMM2 l2norm cur->dout. cur (layer-1 features) is dead here.
  k_ln_all<<<dim3((280000 * 4 + 255) / 256), dim3(256), 0, stream>>>(
      dout, cur, lng, lnb);
  k_gemm_all<<<dim3(BLKTOT), dim3(256), 0, stream>>>(
      cur, pkw, pb1, cur, 36, 1, 0);
  k_gemm_all<<<dim3(BLKTOT), dim3(256), 0, stream>>>(
      cur, pkw, pb2, dout, 39, 0, 1);

  (void)in_sizes; (void)n_in; (void)out_size; (void)ws_size;
}

// Round 20
// 1774.010 us; speedup vs baseline: 1.0361x; 1.0361x over previous
//
#include <hip/hip_runtime.h>
#include <math.h>

// ---------------------------------------------------------------------------
// Heterogeneous GraphSAGE (3 types, 6 relations, D=128, L=3) + MLP head.
// Round 20: R18 sage structure (best measured: two slot dispatches/layer,
// 3-term split-bf16, 32KB swizzled Ms, no barriers, VGPR 60) + R19's proven
// 3-term head (absmax stayed at the 0.001953125 floor) + weight pack
// shrunk to hi/mid only (lo plane never read by 3-term GEMMs).
//
// Node row layout: [performance 0..200000) [artist ..230000) [song ..280000)
// ---------------------------------------------------------------------------

#define NPF 200000
#define NAR 30000
#define NSO 50000
#define NDTOT 560000     // sum of per-relation dst-node counts
#define ETOT  1900000    // total edges
#define VPT 12
#define SCAN_CHUNK (256 * VPT)   // 3072
#define SCAN_NB 183              // ceil(560000/3072)

// per-type 64-row block counts and the merged grid
#define BLKP 3125                // 200000/64
#define BLKA 469                 // ceil(30000/64)
#define BLKS 782                 // ceil(50000/64)
#define BLKTOT (BLKP + BLKA + BLKS)   // 4376

typedef __attribute__((ext_vector_type(8))) short bf16x8;
typedef __attribute__((ext_vector_type(4))) float f32x4;

__device__ __forceinline__ unsigned short f2bf(float f) {
  union { float f; unsigned u; } v; v.f = f;
  unsigned u = v.u;
  u += 0x7FFFu + ((u >> 16) & 1u);
  return (unsigned short)(u >> 16);
}
__device__ __forceinline__ float bf2f(unsigned short h) {
  union { unsigned u; float f; } v; v.u = ((unsigned)h) << 16;
  return v.f;
}

struct BF2 { short h, m; };
__device__ __forceinline__ BF2 split2(float f) {
  BF2 r;
  unsigned short hh = f2bf(f);
  r.h = (short)hh;
  r.m = (short)f2bf(f - bf2f(hh));
  return r;
}

#define MFMA3(ah, am, bh, bm, acc)                                              \
  acc = __builtin_amdgcn_mfma_f32_16x16x32_bf16(ah, bh, acc, 0, 0, 0);          \
  acc = __builtin_amdgcn_mfma_f32_16x16x32_bf16(am, bh, acc, 0, 0, 0);          \
  acc = __builtin_amdgcn_mfma_f32_16x16x32_bf16(ah, bm, acc, 0, 0, 0);

// block -> (type, local block) decode for the merged 4376-block grids
__device__ __forceinline__ void blk_decode(int b, int* t, int* lb) {
  if (b < BLKP)             { *t = 0; *lb = b; }
  else if (b < BLKP + BLKA) { *t = 1; *lb = b - BLKP; }
  else                      { *t = 2; *lb = b - BLKP - BLKA; }
}

// ---------- fused gather x0 = emb[nid] over all 3 types ----------
__global__ void k_gather_all(const int* __restrict__ nidP, const int* __restrict__ nidA,
                             const int* __restrict__ nidS,
                             const float4* __restrict__ embP, const float4* __restrict__ embA,
                             const float4* __restrict__ embS, float4* __restrict__ dst) {
  int i = blockIdx.x * blockDim.x + threadIdx.x;
  if (i >= 280000 * 32) return;
  int r = i >> 5, c = i & 31;
  const int* nid; const float4* emb; int lr;
  if (r < NPF)            { nid = nidP; emb = embP; lr = r; }
  else if (r < NPF + NAR) { nid = nidA; emb = embA; lr = r - NPF; }
  else                    { nid = nidS; emb = embS; lr = r - NPF - NAR; }
  dst[(size_t)r * 32 + c] = emb[(size_t)nid[lr] * 32 + c];
}

// ---------- concatenated CSR build over all 6 relations ----------
__device__ __forceinline__ void edge_decode(int i,
    const int* e0, const int* e1, const int* e2, const int* e3, const int* e4, const int* e5,
    const int** eg, int* lo, int* E, int* co) {
  if (i < 400000)       { *eg = e0; *lo = i;           *E = 400000; *co = 0; }
  else if (i < 800000)  { *eg = e1; *lo = i - 400000;  *E = 400000; *co = 200000; }
  else if (i < 950000)  { *eg = e2; *lo = i - 800000;  *E = 150000; *co = 250000; }
  else if (i < 1350000) { *eg = e3; *lo = i - 950000;  *E = 400000; *co = 300000; }
  else if (i < 1750000) { *eg = e4; *lo = i - 1350000; *E = 400000; *co = 330000; }
  else                  { *eg = e5; *lo = i - 1750000; *E = 150000; *co = 530000; }
}

__global__ void k_count_all(const int* e0, const int* e1, const int* e2,
                            const int* e3, const int* e4, const int* e5,
                            int* __restrict__ cnt) {
  int i = blockIdx.x * blockDim.x + threadIdx.x;
  if (i >= ETOT) return;
  const int* eg; int lo, E, co;
  edge_decode(i, e0, e1, e2, e3, e4, e5, &eg, &lo, &E, &co);
  atomicAdd(&cnt[co + eg[E + lo]], 1);
}

__global__ void k_scan_block(const int* __restrict__ cnt, int n, int* __restrict__ part) {
  __shared__ int sd[256];
  int t = threadIdx.x;
  int base = blockIdx.x * SCAN_CHUNK + t * VPT;
  int s = 0;
#pragma unroll
  for (int i = 0; i < VPT; ++i) { int idx = base + i; if (idx < n) s += cnt[idx]; }
  sd[t] = s; __syncthreads();
  for (int off = 128; off > 0; off >>= 1) { if (t < off) sd[t] += sd[t + off]; __syncthreads(); }
  if (t == 0) part[blockIdx.x] = sd[0];
}

__global__ void k_scan_top(int* part, int nb) {
  __shared__ int sd[256];
  int t = threadIdx.x;
  int v = (t < nb) ? part[t] : 0;
  sd[t] = v; __syncthreads();
  for (int off = 1; off < 256; off <<= 1) {
    int add = (t >= off) ? sd[t - off] : 0;
    __syncthreads();
    sd[t] += add;
    __syncthreads();
  }
  if (t < nb) part[t] = sd[t] - v;  // exclusive
}

// also zeroes cnt so it can be reused as the fill cursor array
__global__ void k_scan_final(int* __restrict__ cnt, int n, const int* __restrict__ part,
                             int* __restrict__ rp, int E) {
  __shared__ int sd[256];
  int t = threadIdx.x;
  int base = blockIdx.x * SCAN_CHUNK + t * VPT;
  int v[VPT]; int s = 0;
#pragma unroll
  for (int i = 0; i < VPT; ++i) { int idx = base + i; v[i] = (idx < n) ? cnt[idx] : 0; s += v[i]; }
  sd[t] = s; __syncthreads();
  for (int off = 1; off < 256; off <<= 1) {
    int add = (t >= off) ? sd[t - off] : 0;
    __syncthreads();
    sd[t] += add;
    __syncthreads();
  }
  int run = part[blockIdx.x] + sd[t] - s;
#pragma unroll
  for (int i = 0; i < VPT; ++i) {
    int idx = base + i;
    if (idx < n) { rp[idx] = run; cnt[idx] = 0; }
    run += v[i];
  }
  if (blockIdx.x == 0 && t == 0) rp[n] = E;
}

__global__ void k_fill_all(const int* e0, const int* e1, const int* e2,
                           const int* e3, const int* e4, const int* e5,
                           const int* __restrict__ rp, int* __restrict__ cur,
                           int* __restrict__ col) {
  int i = blockIdx.x * blockDim.x + threadIdx.x;
  if (i >= ETOT) return;
  const int* eg; int lo, E, co;
  edge_decode(i, e0, e1, e2, e3, e4, e5, &eg, &lo, &E, &co);
  int d = co + eg[E + lo];
  int p = atomicAdd(&cur[d], 1);
  col[rp[d] + p] = eg[lo];
}

// ---------- pack weights into MFMA B-fragment order, bf16 hi/mid ----------
// matrix m: [0,18)=Wl[layer*6+r], [18,36)=Wr, [36,39)=pw1[type], [39,42)=pw2[type]
// per-matrix block (32768 ushorts): hi[16384], mid[16384].
#define PKSTRIDE 32768
__global__ void k_packW(const float* __restrict__ Wl, const float* __restrict__ Wr,
                        const float* __restrict__ pw1, const float* __restrict__ pw2,
                        unsigned short* __restrict__ pk) {
  int gid = blockIdx.x * blockDim.x + threadIdx.x;
  if (gid >= 42 * 4 * 8 * 64) return;
  int lane = gid & 63;
  int t = (gid >> 6) & 7;
  int s = (gid >> 9) & 3;
  int m = gid >> 11;
  const float* src;
  if (m < 18) src = Wl + (size_t)m * 16384;
  else if (m < 36) src = Wr + (size_t)(m - 18) * 16384;
  else if (m < 39) src = pw1 + (size_t)(m - 36) * 16384;
  else src = pw2 + (size_t)(m - 39) * 16384;
  int n = t * 16 + (lane & 15);
  int k0 = s * 32 + (lane >> 4) * 8;
  unsigned short* hi = pk + (size_t)m * PKSTRIDE + ((size_t)(s * 8 + t) * 64 + lane) * 8;
  unsigned short* mid = hi + 16384;
#pragma unroll
  for (int j = 0; j < 8; ++j) {
    float f = src[(size_t)(k0 + j) * 128 + n];
    BF2 w = split2(f);
    hi[j] = (unsigned short)w.h;
    mid[j] = (unsigned short)w.m;
  }
}

// ---------- merged fused agg + SAGE over all 3 dst types, one relation slot ----------
// slot 0: first-writer relations {perf<-artist(r0), artist<-perf(r3), song<-perf(r1)}, store.
// slot 1: accumulators {perf<-song(r4), artist<-song(r5), song<-artist(r2)}, +relu?.
// Ms is [64][128] f32 (exactly 32KB) with a 16B-chunk XOR swizzle
// (chunk ^ (row&7)). No __syncthreads (wave-private stripes).
// Phase B: 3-term split-bf16.
__global__ __launch_bounds__(256) void k_sage_merged(
    const int* __restrict__ rp, const int* __restrict__ col,
    const float* __restrict__ xin, float* __restrict__ xout,
    const unsigned short* __restrict__ pkw, const float* __restrict__ bl,
    int layer, int slot, int relu_out) {
  __shared__ float Ms[64 * 128];   // 32768 B exactly
  static const int RELSLOT[2][3] = {{0, 3, 1}, {4, 5, 2}};
  static const int SRCT[2][3]    = {{1, 0, 0}, {2, 2, 1}};
  static const int CNT_OFF[6] = {0, 200000, 250000, 300000, 330000, 530000};
  static const int TOFFc[3] = {0, NPF, NPF + NAR};
  static const int TNc[3]   = {NPF, NAR, NSO};
  int ty, lb;
  blk_decode(blockIdx.x, &ty, &lb);
  int rel = RELSLOT[slot][ty];
  int m = layer * 6 + rel;
  const int* rpt = rp + CNT_OFF[rel];
  const float* xsrc = xin + (size_t)TOFFc[SRCT[slot][ty]] * 128;
  const float* xdst = xin + (size_t)TOFFc[ty] * 128;
  float* outp = xout + (size_t)TOFFc[ty] * 128;
  const unsigned short* pkl = pkw + (size_t)m * PKSTRIDE;
  const unsigned short* pkr = pkw + (size_t)(18 + m) * PKSTRIDE;
  const float* blv = bl + (size_t)m * 128;
  int n_dst = TNc[ty];
  int first = (slot == 0);

  int lane = threadIdx.x & 63;
  int wave = threadIdx.x >> 6;
  int row0b = lb * 64;

  // ---- phase A: segment mean into this wave's Ms stripe (swizzled) ----
  {
    int g = lane >> 4, li = lane & 15;
    int c0 = li * 8;
    int bb[4], ne[4];
    int maxd = 0;
#pragma unroll
    for (int i = 0; i < 4; ++i) {
      int d = row0b + wave * 16 + g * 4 + i;
      int b = 0, e = 0;
      if (d < n_dst) { b = rpt[d]; e = rpt[d + 1]; }
      bb[i] = b; ne[i] = e - b;
      maxd = max(maxd, e - b);
    }
    f32x4 a0[4], a1[4];
#pragma unroll
    for (int i = 0; i < 4; ++i) { a0[i] = (f32x4){0.f,0.f,0.f,0.f}; a1[i] = (f32x4){0.f,0.f,0.f,0.f}; }
    int nc[4];
#pragma unroll
    for (int i = 0; i < 4; ++i) nc[i] = (0 < ne[i]) ? col[bb[i]] : 0;
    for (int k = 0; k < maxd; ++k) {
      int cc[4];
#pragma unroll
      for (int i = 0; i < 4; ++i) cc[i] = nc[i];
#pragma unroll
      for (int i = 0; i < 4; ++i) nc[i] = (k + 1 < ne[i]) ? col[bb[i] + k + 1] : 0;
#pragma unroll
      for (int i = 0; i < 4; ++i) {
        if (k < ne[i]) {
          const float* sp = xsrc + (size_t)cc[i] * 128 + c0;
          float4 v0 = *(const float4*)sp;
          float4 v1 = *(const float4*)(sp + 4);
          a0[i][0] += v0.x; a0[i][1] += v0.y; a0[i][2] += v0.z; a0[i][3] += v0.w;
          a1[i][0] += v1.x; a1[i][1] += v1.y; a1[i][2] += v1.z; a1[i][3] += v1.w;
        }
      }
    }
#pragma unroll
    for (int i = 0; i < 4; ++i) {
      float inv = (ne[i] > 0) ? 1.0f / (float)ne[i] : 0.0f;
      int lr = wave * 16 + g * 4 + i;
      float4* Mrow = (float4*)&Ms[lr * 128];
      int sw = lr & 7;
      Mrow[(li * 2) ^ sw]     = make_float4(a0[i][0]*inv, a0[i][1]*inv, a0[i][2]*inv, a0[i][3]*inv);
      Mrow[(li * 2 + 1) ^ sw] = make_float4(a1[i][0]*inv, a1[i][1]*inv, a1[i][2]*inv, a1[i][3]*inv);
    }
  }
  // no __syncthreads(): each wave reads only the stripe it wrote

  // ---- phase B: 3-term split-bf16 MFMA ----
  int row0 = row0b + wave * 16;
  int cg = lane & 15, qg = lane >> 4;
  int ar = min(row0 + cg, n_dst - 1);
  int lar = wave * 16 + cg;
  int kb = qg * 8;
  const float4* Mlar = (const float4*)&Ms[lar * 128];
  int swl = lar & 7;

  f32x4 acc[8];
#pragma unroll
  for (int t = 0; t < 8; ++t) acc[t] = (f32x4){0.f, 0.f, 0.f, 0.f};

#pragma unroll
  for (int sm = 0; sm < 2; ++sm) {
    const unsigned short* pk = sm ? pkr : pkl;
#pragma unroll
    for (int s = 0; s < 4; ++s) {
      float4 f0, f1;
      if (sm) {
        const float* ap = xdst + (size_t)ar * 128 + s * 32 + kb;
        f0 = *(const float4*)ap;
        f1 = *(const float4*)(ap + 4);
      } else {
        int ch = s * 8 + qg * 2;
        f0 = Mlar[ch ^ swl];
        f1 = Mlar[(ch + 1) ^ swl];
      }
      float fa[8] = {f0.x, f0.y, f0.z, f0.w, f1.x, f1.y, f1.z, f1.w};
      bf16x8 ah, am;
#pragma unroll
      for (int j = 0; j < 8; ++j) {
        BF2 w = split2(fa[j]);
        ah[j] = w.h; am[j] = w.m;
      }
      const unsigned short* pb = pk + (size_t)s * 4096 + (size_t)lane * 8;
#pragma unroll
      for (int t = 0; t < 8; ++t) {
        bf16x8 bh = *(const bf16x8*)(pb + (size_t)t * 512);
        bf16x8 bm = *(const bf16x8*)(pb + (size_t)t * 512 + 16384);
        MFMA3(ah, am, bh, bm, acc[t]);
      }
    }
  }

  // bias
#pragma unroll
  for (int t = 0; t < 8; ++t) {
    float bv = blv[t * 16 + cg];
#pragma unroll
    for (int j = 0; j < 4; ++j) acc[t][j] += bv;
  }
  // l2norm + store/accumulate
  float ss[4];
#pragma unroll
  for (int j = 0; j < 4; ++j) {
    float s = 0.f;
#pragma unroll
    for (int t = 0; t < 8; ++t) s += acc[t][j] * acc[t][j];
    s += __shfl_xor(s, 1); s += __shfl_xor(s, 2);
    s += __shfl_xor(s, 4); s += __shfl_xor(s, 8);
    ss[j] = 1.0f / fmaxf(sqrtf(s), 1e-12f);
  }
#pragma unroll
  for (int j = 0; j < 4; ++j) {
    int r = row0 + qg * 4 + j;
    if (r < n_dst) {
      float* p = outp + (size_t)r * 128 + cg;
      if (first) {
#pragma unroll
        for (int t = 0; t < 8; ++t) p[t * 16] = acc[t][j] * ss[j];
      } else {
#pragma unroll
        for (int t = 0; t < 8; ++t) {
          float v = p[t * 16] + acc[t][j] * ss[j];
          if (relu_out) v = fmaxf(v, 0.f);
          p[t * 16] = v;
        }
      }
    }
  }
}

// ---------- merged LayerNorm over all 280000 rows ----------
__global__ __launch_bounds__(256) void k_ln_all(const float* __restrict__ in,
                                                float* __restrict__ out,
                                                const float* __restrict__ lng,
                                                const float* __restrict__ lnb) {
  int gid = blockIdx.x * blockDim.x + threadIdx.x;
  int r = gid >> 2, q = gid & 3;
  if (r >= NPF + NAR + NSO) return;
  int ty = (r < NPF) ? 0 : ((r < NPF + NAR) ? 1 : 2);
  const float* g = lng + ty * 128;
  const float* bvec = lnb + ty * 128;
  float v[32];
#pragma unroll
  for (int j = 0; j < 8; ++j) {
    float4 t4 = *(const float4*)(in + (size_t)r * 128 + q * 32 + j * 4);
    v[4 * j] = t4.x; v[4 * j + 1] = t4.y; v[4 * j + 2] = t4.z; v[4 * j + 3] = t4.w;
  }
  float s = 0.f, sq = 0.f;
#pragma unroll
  for (int j = 0; j < 32; ++j) { s += v[j]; sq += v[j] * v[j]; }
  s  += __shfl_xor(s, 1);  s  += __shfl_xor(s, 2);
  sq += __shfl_xor(sq, 1); sq += __shfl_xor(sq, 2);
  float mu = s * 0.0078125f;
  float var = sq * 0.0078125f - mu * mu;
  float rs = rsqrtf(var + 1e-5f);
#pragma unroll
  for (int j = 0; j < 8; ++j) {
    float o[4];
#pragma unroll
    for (int k = 0; k < 4; ++k) {
      int c = q * 32 + j * 4 + k;
      o[k] = (v[j * 4 + k] - mu) * rs * g[c] + bvec[c];
    }
    *(float4*)(out + (size_t)r * 128 + q * 32 + j * 4) = make_float4(o[0], o[1], o[2], o[3]);
  }
}

// ---------- merged head GEMM over all 3 types (3-term split) ----------
// stage 0: relu(LN@pw1+pb1)  (pk base 36);  stage 1: l2norm(h1@pw2+pb2) (pk base 39).
// In-place safe when outp==A.
__global__ __launch_bounds__(256) void k_gemm_all(
    const float* __restrict__ A, const unsigned short* __restrict__ pkw,
    const float* __restrict__ biasb, float* __restrict__ outp,
    int pkbase, int relu, int l2n) {
  static const int TOFFc[3] = {0, NPF, NPF + NAR};
  static const int TNc[3]   = {NPF, NAR, NSO};
  int ty, lb;
  blk_decode(blockIdx.x, &ty, &lb);
  const unsigned short* pk = pkw + (size_t)(pkbase + ty) * PKSTRIDE;
  const float* bias = biasb + ty * 128;
  const float* At = A + (size_t)TOFFc[ty] * 128;
  float* outt = outp + (size_t)TOFFc[ty] * 128;
  int n = TNc[ty];

  int lane = threadIdx.x & 63;
  int wave = threadIdx.x >> 6;
  int row0 = lb * 64 + wave * 16;
  int cg = lane & 15, qg = lane >> 4;
  int ar = min(row0 + cg, n - 1);
  int kb = qg * 8;

  f32x4 acc[8];
#pragma unroll
  for (int t = 0; t < 8; ++t) acc[t] = (f32x4){0.f, 0.f, 0.f, 0.f};

#pragma unroll
  for (int s = 0; s < 4; ++s) {
    const float* ap = At + (size_t)ar * 128 + s * 32 + kb;
    float4 f0 = *(const float4*)ap;
    float4 f1 = *(const float4*)(ap + 4);
    float fa[8] = {f0.x, f0.y, f0.z, f0.w, f1.x, f1.y, f1.z, f1.w};
    bf16x8 ah, am;
#pragma unroll
    for (int j = 0; j < 8; ++j) {
      BF2 w = split2(fa[j]);
      ah[j] = w.h; am[j] = w.m;
    }
    const unsigned short* pb = pk + (size_t)s * 4096 + (size_t)lane * 8;
#pragma unroll
    for (int t = 0; t < 8; ++t) {
      bf16x8 bh = *(const bf16x8*)(pb + (size_t)t * 512);
      bf16x8 bm = *(const bf16x8*)(pb + (size_t)t * 512 + 16384);
      MFMA3(ah, am, bh, bm, acc[t]);
    }
  }

#pragma unroll
  for (int t = 0; t < 8; ++t) {
    float bv = bias[t * 16 + cg];
#pragma unroll
    for (int j = 0; j < 4; ++j) acc[t][j] += bv;
  }

  float ss[4];
  if (l2n) {
#pragma unroll
    for (int j = 0; j < 4; ++j) {
      float s = 0.f;
#pragma unroll
      for (int t = 0; t < 8; ++t) s += acc[t][j] * acc[t][j];
      s += __shfl_xor(s, 1); s += __shfl_xor(s, 2);
      s += __shfl_xor(s, 4); s += __shfl_xor(s, 8);
      ss[j] = 1.0f / fmaxf(sqrtf(s), 1e-12f);
    }
  } else {
#pragma unroll
    for (int j = 0; j < 4; ++j) ss[j] = 1.0f;
  }

#pragma unroll
  for (int j = 0; j < 4; ++j) {
    int r = row0 + qg * 4 + j;
    if (r < n) {
      float* p = outt + (size_t)r * 128 + cg;
#pragma unroll
      for (int t = 0; t < 8; ++t) {
        float v = acc[t][j] * ss[j];
        if (relu) v = fmaxf(v, 0.f);
        p[t * 16] = v;
      }
    }
  }
}

// ---------------------------------------------------------------------------
extern "C" void kernel_launch(void* const* d_in, const int* in_sizes, int n_in,
                              void* d_out, int out_size, void* d_ws, size_t ws_size,
                              hipStream_t stream) {
  const int* nid[3] = {(const int*)d_in[0], (const int*)d_in[1], (const int*)d_in[2]};
  const int* eg[6];
  for (int r = 0; r < 6; ++r) eg[r] = (const int*)d_in[3 + r];
  const float* emb[3] = {(const float*)d_in[9], (const float*)d_in[10], (const float*)d_in[11]};
  const float* Wl  = (const float*)d_in[12];
  const float* bl  = (const float*)d_in[13];
  const float* Wr  = (const float*)d_in[14];
  const float* lng = (const float*)d_in[15];
  const float* lnb = (const float*)d_in[16];
  const float* pw1 = (const float*)d_in[17];
  const float* pb1 = (const float*)d_in[18];
  const float* pw2 = (const float*)d_in[19];
  const float* pb2 = (const float*)d_in[20];

  // workspace layout (~159 MB)
  float* cur = (float*)d_ws;                          // 280000*128 f32 (features + head scratch)
  int* col   = (int*)(cur + (size_t)280000 * 128);    // ETOT
  int* rp    = col + ETOT;                            // NDTOT+1
  int* cnt   = rp + NDTOT + 1;                        // NDTOT (counts, then fill cursors)
  int* part  = cnt + NDTOT;                           // 256
  size_t pk_off = ((size_t)((char*)(part + 256) - (char*)d_ws) + 255) & ~(size_t)255;
  unsigned short* pkw = (unsigned short*)((char*)d_ws + pk_off);  // 42*32768 ushorts = 2.75 MB
  float* dout = (float*)d_out;

  // pack all weights (42 matrices) into MFMA fragment order, bf16 hi/mid
  k_packW<<<dim3(336), dim3(256), 0, stream>>>(Wl, Wr, pw1, pw2, pkw);

  // x0 = emb[nid] (all types, one kernel)
  k_gather_all<<<dim3((280000 * 32 + 255) / 256), dim3(256), 0, stream>>>(
      nid[0], nid[1], nid[2],
      (const float4*)emb[0], (const float4*)emb[1], (const float4*)emb[2],
      (float4*)cur);

  // concatenated CSR build (count -> scan (zeroes cnt) -> fill)
  hipMemsetAsync(cnt, 0, (size_t)NDTOT * 4, stream);
  k_count_all<<<dim3((ETOT + 255) / 256), dim3(256), 0, stream>>>(
      eg[0], eg[1], eg[2], eg[3], eg[4], eg[5], cnt);
  k_scan_block<<<dim3(SCAN_NB), dim3(256), 0, stream>>>(cnt, NDTOT, part);
  k_scan_top<<<dim3(1), dim3(256), 0, stream>>>(part, SCAN_NB);
  k_scan_final<<<dim3(SCAN_NB), dim3(256), 0, stream>>>(cnt, NDTOT, part, rp, ETOT);
  k_fill_all<<<dim3((ETOT + 255) / 256), dim3(256), 0, stream>>>(
      eg[0], eg[1], eg[2], eg[3], eg[4], eg[5], rp, cnt, col);

  // GNN layers; ping-pong cur <-> d_out (layer0: cur->dout, 1: dout->cur, 2: cur->dout)
  // two merged dispatches per layer (slot 0 = store, slot 1 = accumulate+relu)
  for (int layer = 0; layer < 3; ++layer) {
    float* xin  = (layer == 1) ? dout : cur;
    float* xout = (layer == 1) ? cur  : dout;
    int relu_o = (layer < 2) ? 1 : 0;
    k_sage_merged<<<dim3(BLKTOT), dim3(256), 0, stream>>>(
        rp, col, xin, xout, pkw, bl, layer, 0, relu_o);
    k_sage_merged<<<dim3(BLKTOT), dim3(256), 0, stream>>>(
        rp, col, xin, xout, pkw, bl, layer, 1, relu_o);
  }

  // head (merged over types): LN dout->cur, GEMM1 relu cur->cur (in-place),
  // GEMM2 l2norm cur->dout. cur (layer-1 features) is dead here.
  k_ln_all<<<dim3((280000 * 4 + 255) / 256), dim3(256), 0, stream>>>(
      dout, cur, lng, lnb);
  k_gemm_all<<<dim3(BLKTOT), dim3(256), 0, stream>>>(
      cur, pkw, pb1, cur, 36, 1, 0);
  k_gemm_all<<<dim3(BLKTOT), dim3(256), 0, stream>>>(
      cur, pkw, pb2, dout, 39, 0, 1);

  (void)in_sizes; (void)n_in; (void)out_size; (void)ws_size;
}